// Round 1
// baseline (392.547 us; speedup 1.0000x reference)
//
#include <hip/hip_runtime.h>
#include <math.h>

#define N_NODES 50000
#define N_EDGES 640000
#define FDIM 128
#define NCLS 16
#define BN_EPS 1e-5f

// ---------------- CSR build ----------------

__global__ __launch_bounds__(256) void zero_kernel(int* __restrict__ a, int* __restrict__ b) {
    int gid = blockIdx.x * 256 + threadIdx.x;
    if (gid < N_NODES) { a[gid] = 0; b[gid] = 0; }
}

__global__ __launch_bounds__(256) void count_deg_kernel(const int* __restrict__ dst, int* __restrict__ deg) {
    int gid = blockIdx.x * 256 + threadIdx.x;
    if (gid < N_EDGES) atomicAdd(&deg[dst[gid]], 1);
}

__global__ __launch_bounds__(256) void dinv_kernel(const int* __restrict__ deg, float* __restrict__ dinv) {
    int gid = blockIdx.x * 256 + threadIdx.x;
    if (gid < N_NODES) dinv[gid] = rsqrtf((float)(deg[gid] + 1));  // +1 self loop
}

__global__ __launch_bounds__(256) void scan_block_kernel(const int* __restrict__ deg,
                                                         int* __restrict__ offs,
                                                         int* __restrict__ partials) {
    __shared__ int s[256];
    int tid = threadIdx.x;
    int gid = blockIdx.x * 256 + tid;
    int v = (gid < N_NODES) ? deg[gid] : 0;
    s[tid] = v;
    __syncthreads();
    for (int off = 1; off < 256; off <<= 1) {
        int t = (tid >= off) ? s[tid - off] : 0;
        __syncthreads();
        s[tid] += t;
        __syncthreads();
    }
    if (gid < N_NODES) offs[gid] = s[tid] - v;   // exclusive
    if (tid == 255) partials[blockIdx.x] = s[255];
}

__global__ __launch_bounds__(256) void scan_partials_kernel(int* __restrict__ partials,
                                                            int* __restrict__ offs, int nb) {
    __shared__ int s[256];
    int tid = threadIdx.x;
    int v = (tid < nb) ? partials[tid] : 0;
    s[tid] = v;
    __syncthreads();
    for (int off = 1; off < 256; off <<= 1) {
        int t = (tid >= off) ? s[tid - off] : 0;
        __syncthreads();
        s[tid] += t;
        __syncthreads();
    }
    if (tid < nb) partials[tid] = s[tid] - v;    // exclusive
    if (tid == 255) offs[N_NODES] = s[255];      // total == N_EDGES
}

__global__ __launch_bounds__(256) void scan_add_kernel(int* __restrict__ offs, const int* __restrict__ partials) {
    int gid = blockIdx.x * 256 + threadIdx.x;
    if (gid < N_NODES) offs[gid] += partials[blockIdx.x];
}

__global__ __launch_bounds__(256) void fill_csr_kernel(const int* __restrict__ src,
                                                       const int* __restrict__ dst,
                                                       const int* __restrict__ offs,
                                                       int* __restrict__ cursor,
                                                       int* __restrict__ csr_src) {
    int gid = blockIdx.x * 256 + threadIdx.x;
    if (gid < N_EDGES) {
        int d = dst[gid];
        int pos = offs[d] + atomicAdd(&cursor[d], 1);
        csr_src[pos] = src[gid];
    }
}

// ---------------- GEMM 128x128 (f32 vector) ----------------
// Block: 256 threads, 64 rows x 128 cols. Thread tile: 4 rows x 8 cols.
__global__ __launch_bounds__(256) void gemm128_kernel(const float* __restrict__ X,
                                                      const float* __restrict__ W,
                                                      float* __restrict__ Y, int M) {
    __shared__ float sW[128 * 128];          // 64 KiB, unpadded (float4 reads)
    __shared__ float sX[64 * 129];           // pad 129 -> conflict-free b32 reads
    int tid = threadIdx.x;

    const float4* W4 = (const float4*)W;
    float4* sW4 = (float4*)sW;
#pragma unroll
    for (int i = 0; i < 16; i++) sW4[tid + i * 256] = W4[tid + i * 256];

    int r0 = blockIdx.x * 64;
    const float4* X4 = (const float4*)X;
#pragma unroll
    for (int i = 0; i < 8; i++) {
        int fi = tid + i * 256;
        int row = fi >> 5, c4 = fi & 31;
        float4 v = make_float4(0.f, 0.f, 0.f, 0.f);
        if (r0 + row < M) v = X4[(size_t)(r0 + row) * 32 + c4];
        float* p = &sX[row * 129 + c4 * 4];
        p[0] = v.x; p[1] = v.y; p[2] = v.z; p[3] = v.w;
    }
    __syncthreads();

    int colg = tid & 15, rowt = tid >> 4;
    int c = colg * 8;
    float acc[4][8];
#pragma unroll
    for (int i = 0; i < 4; i++)
#pragma unroll
        for (int j = 0; j < 8; j++) acc[i][j] = 0.f;

#pragma unroll 4
    for (int k = 0; k < 128; k++) {
        float4 w0 = sW4[k * 32 + colg * 2];
        float4 w1 = sW4[k * 32 + colg * 2 + 1];
        float x0 = sX[(rowt * 4 + 0) * 129 + k];
        float x1 = sX[(rowt * 4 + 1) * 129 + k];
        float x2 = sX[(rowt * 4 + 2) * 129 + k];
        float x3 = sX[(rowt * 4 + 3) * 129 + k];
        float xs[4] = {x0, x1, x2, x3};
#pragma unroll
        for (int i = 0; i < 4; i++) {
            acc[i][0] += xs[i] * w0.x; acc[i][1] += xs[i] * w0.y;
            acc[i][2] += xs[i] * w0.z; acc[i][3] += xs[i] * w0.w;
            acc[i][4] += xs[i] * w1.x; acc[i][5] += xs[i] * w1.y;
            acc[i][6] += xs[i] * w1.z; acc[i][7] += xs[i] * w1.w;
        }
    }

#pragma unroll
    for (int i = 0; i < 4; i++) {
        int row = r0 + rowt * 4 + i;
        if (row < M) {
            float4* Yp = (float4*)(Y + (size_t)row * 128 + c);
            Yp[0] = make_float4(acc[i][0], acc[i][1], acc[i][2], acc[i][3]);
            Yp[1] = make_float4(acc[i][4], acc[i][5], acc[i][6], acc[i][7]);
        }
    }
}

// ---------------- Aggregation (pull-based, wave per node) ----------------
__global__ __launch_bounds__(256) void aggregate_kernel(const float* __restrict__ H,
                                                        const int* __restrict__ csr_src,
                                                        const int* __restrict__ offs,
                                                        const float* __restrict__ dinv,
                                                        const float* __restrict__ bias,
                                                        const float* __restrict__ bn_mean,
                                                        const float* __restrict__ bn_var,
                                                        const float* __restrict__ bn_gamma,
                                                        const float* __restrict__ bn_beta,
                                                        float* __restrict__ Y,
                                                        int apply_bn) {
    int wv = threadIdx.x >> 6, lane = threadIdx.x & 63;
    int node = blockIdx.x * 4 + wv;            // 12500*4 == 50000, no guard needed
    int beg = offs[node], end = offs[node + 1];
    float di = dinv[node];

    const float2* Hn = (const float2*)(H + (size_t)node * FDIM);
    float2 hv = Hn[lane];
    float2 acc;
    acc.x = hv.x * di * di;                    // self loop: norm = dinv^2
    acc.y = hv.y * di * di;

    int e = beg;
    for (; e + 1 < end; e += 2) {
        int s0 = csr_src[e], s1 = csr_src[e + 1];
        float w0 = dinv[s0] * di, w1 = dinv[s1] * di;
        const float2* p0 = (const float2*)(H + (size_t)s0 * FDIM);
        const float2* p1 = (const float2*)(H + (size_t)s1 * FDIM);
        float2 v0 = p0[lane], v1 = p1[lane];
        acc.x += v0.x * w0 + v1.x * w1;
        acc.y += v0.y * w0 + v1.y * w1;
    }
    if (e < end) {
        int s0 = csr_src[e];
        float w0 = dinv[s0] * di;
        const float2* p0 = (const float2*)(H + (size_t)s0 * FDIM);
        float2 v0 = p0[lane];
        acc.x += v0.x * w0;
        acc.y += v0.y * w0;
    }

    int c0 = lane * 2, c1 = c0 + 1;
    acc.x += bias[c0];
    acc.y += bias[c1];
    if (apply_bn) {
        float sc0 = bn_gamma[c0] * rsqrtf(bn_var[c0] + BN_EPS);
        float sc1 = bn_gamma[c1] * rsqrtf(bn_var[c1] + BN_EPS);
        acc.x = (acc.x - bn_mean[c0]) * sc0 + bn_beta[c0];
        acc.y = (acc.y - bn_mean[c1]) * sc1 + bn_beta[c1];
        acc.x = fmaxf(acc.x, 0.f);
        acc.y = fmaxf(acc.y, 0.f);
    }
    ((float2*)(Y + (size_t)node * FDIM))[lane] = acc;
}

// ---------------- Final GEMM 128x16 + bias ----------------
__global__ __launch_bounds__(256) void final_gemm_kernel(const float* __restrict__ X,
                                                         const float* __restrict__ Wc,
                                                         const float* __restrict__ bc,
                                                         float* __restrict__ Y, int M) {
    __shared__ float sX[16 * 132];
    __shared__ float sW[128 * 16];
    int tid = threadIdx.x;

    const float4* W4 = (const float4*)Wc;
    float4* sW4 = (float4*)sW;
    sW4[tid] = W4[tid];
    sW4[tid + 256] = W4[tid + 256];

    int r0 = blockIdx.x * 16;
    const float4* X4 = (const float4*)X;
#pragma unroll
    for (int i = 0; i < 2; i++) {
        int fi = tid + i * 256;
        int row = fi >> 5, c4 = fi & 31;
        float4 v = make_float4(0.f, 0.f, 0.f, 0.f);
        if (r0 + row < M) v = X4[(size_t)(r0 + row) * 32 + c4];
        float* p = &sX[row * 132 + c4 * 4];
        p[0] = v.x; p[1] = v.y; p[2] = v.z; p[3] = v.w;
    }
    __syncthreads();

    int c = tid & 15, rl = tid >> 4;
    int row = r0 + rl;
    float acc = 0.f;
#pragma unroll 8
    for (int k = 0; k < 128; k++) acc += sX[rl * 132 + k] * sW[k * 16 + c];
    if (row < M) Y[(size_t)row * NCLS + c] = acc + bc[c];
}

// ---------------- Launch ----------------
extern "C" void kernel_launch(void* const* d_in, const int* in_sizes, int n_in,
                              void* d_out, int out_size, void* d_ws, size_t ws_size,
                              hipStream_t stream) {
    const float* seq   = (const float*)d_in[0];
    const int*   eidx  = (const int*)d_in[1];
    const float* W1    = (const float*)d_in[2];
    const float* b1    = (const float*)d_in[3];
    const float* gamma = (const float*)d_in[4];
    const float* beta  = (const float*)d_in[5];
    const float* rmean = (const float*)d_in[6];
    const float* rvar  = (const float*)d_in[7];
    const float* W2    = (const float*)d_in[8];
    const float* b2    = (const float*)d_in[9];
    const float* Wc    = (const float*)d_in[10];
    const float* bc    = (const float*)d_in[11];
    float* out = (float*)d_out;

    const int* src = eidx;            // edge_index[0]
    const int* dst = eidx + N_EDGES;  // edge_index[1]

    // workspace carve-up (256B aligned)
    char* ws = (char*)d_ws;
    size_t off = 0;
    auto alloc = [&](size_t bytes) -> void* {
        void* p = ws + off;
        off = (off + bytes + 255) & ~(size_t)255;
        return p;
    };
    int*   deg      = (int*)alloc(N_NODES * 4);
    int*   cursor   = (int*)alloc(N_NODES * 4);
    int*   offs     = (int*)alloc((N_NODES + 1) * 4);
    int*   partials = (int*)alloc(256 * 4);
    float* dinv     = (float*)alloc(N_NODES * 4);
    int*   csr_src  = (int*)alloc(N_EDGES * 4);
    float* bufA     = (float*)alloc((size_t)N_NODES * FDIM * 4);
    float* bufB     = (float*)alloc((size_t)N_NODES * FDIM * 4);
    float* bufC     = (float*)alloc((size_t)N_NODES * FDIM * 4);

    const int NB_N = (N_NODES + 255) / 256;   // 196
    const int NB_E = (N_EDGES + 255) / 256;   // 2500

    zero_kernel<<<NB_N, 256, 0, stream>>>(deg, cursor);
    count_deg_kernel<<<NB_E, 256, 0, stream>>>(dst, deg);
    dinv_kernel<<<NB_N, 256, 0, stream>>>(deg, dinv);
    scan_block_kernel<<<NB_N, 256, 0, stream>>>(deg, offs, partials);
    scan_partials_kernel<<<1, 256, 0, stream>>>(partials, offs, NB_N);
    scan_add_kernel<<<NB_N, 256, 0, stream>>>(offs, partials);
    fill_csr_kernel<<<NB_E, 256, 0, stream>>>(src, dst, offs, cursor, csr_src);

    // layer 1: h = seq @ W1 ; agg + b1 + BN + ReLU
    gemm128_kernel<<<(N_NODES + 63) / 64, 256, 0, stream>>>(seq, W1, bufA, N_NODES);
    aggregate_kernel<<<N_NODES / 4, 256, 0, stream>>>(bufA, csr_src, offs, dinv,
                                                      b1, rmean, rvar, gamma, beta,
                                                      bufB, 1);
    // layer 2: h = x2 @ W2 ; agg + b2
    gemm128_kernel<<<(N_NODES + 63) / 64, 256, 0, stream>>>(bufB, W2, bufA, N_NODES);
    aggregate_kernel<<<N_NODES / 4, 256, 0, stream>>>(bufA, csr_src, offs, dinv,
                                                      b2, rmean, rvar, gamma, beta,
                                                      bufC, 0);
    // classifier
    final_gemm_kernel<<<N_NODES / 16, 256, 0, stream>>>(bufC, Wc, bc, out, N_NODES);
}

// Round 2
// 281.314 us; speedup vs baseline: 1.3954x; 1.3954x over previous
//
#include <hip/hip_runtime.h>
#include <math.h>

#define N_NODES 50000
#define N_EDGES 640000
#define FDIM 128
#define NCLS 16
#define BN_EPS 1e-5f

// ---------------- CSR build ----------------

__global__ __launch_bounds__(256) void zero_kernel(int* __restrict__ a, int* __restrict__ b) {
    int gid = blockIdx.x * 256 + threadIdx.x;
    if (gid < N_NODES) { a[gid] = 0; b[gid] = 0; }
}

__global__ __launch_bounds__(256) void count_deg_kernel(const int* __restrict__ dst, int* __restrict__ deg) {
    int gid = blockIdx.x * 256 + threadIdx.x;
    if (gid < N_EDGES) atomicAdd(&deg[dst[gid]], 1);
}

// block-level exclusive scan of deg; also emits dinv = rsqrt(deg+1)
__global__ __launch_bounds__(256) void scan_block_kernel(const int* __restrict__ deg,
                                                         int* __restrict__ offs,
                                                         int* __restrict__ partials,
                                                         float* __restrict__ dinv) {
    __shared__ int s[256];
    int tid = threadIdx.x;
    int gid = blockIdx.x * 256 + tid;
    int v = (gid < N_NODES) ? deg[gid] : 0;
    if (gid < N_NODES) dinv[gid] = rsqrtf((float)(v + 1));  // +1 self loop
    s[tid] = v;
    __syncthreads();
    for (int off = 1; off < 256; off <<= 1) {
        int t = (tid >= off) ? s[tid - off] : 0;
        __syncthreads();
        s[tid] += t;
        __syncthreads();
    }
    if (gid < N_NODES) offs[gid] = s[tid] - v;   // exclusive
    if (tid == 255) partials[blockIdx.x] = s[255];
}

__global__ __launch_bounds__(256) void scan_partials_kernel(int* __restrict__ partials,
                                                            int* __restrict__ offs, int nb) {
    __shared__ int s[256];
    int tid = threadIdx.x;
    int v = (tid < nb) ? partials[tid] : 0;
    s[tid] = v;
    __syncthreads();
    for (int off = 1; off < 256; off <<= 1) {
        int t = (tid >= off) ? s[tid - off] : 0;
        __syncthreads();
        s[tid] += t;
        __syncthreads();
    }
    if (tid < nb) partials[tid] = s[tid] - v;    // exclusive
    if (tid == 255) offs[N_NODES] = s[255];      // total == N_EDGES
}

__global__ __launch_bounds__(256) void scan_add_kernel(int* __restrict__ offs, const int* __restrict__ partials) {
    int gid = blockIdx.x * 256 + threadIdx.x;
    if (gid < N_NODES) offs[gid] += partials[blockIdx.x];
}

__global__ __launch_bounds__(256) void fill_csr_kernel(const int* __restrict__ src,
                                                       const int* __restrict__ dst,
                                                       const int* __restrict__ offs,
                                                       int* __restrict__ cursor,
                                                       int* __restrict__ csr_src) {
    int gid = blockIdx.x * 256 + threadIdx.x;
    if (gid < N_EDGES) {
        int d = dst[gid];
        int pos = offs[d] + atomicAdd(&cursor[d], 1);
        csr_src[pos] = src[gid];
    }
}

// ---------------- fold W2c = W2 @ Wc, bc2 = b2 @ Wc + bc ----------------
__global__ __launch_bounds__(256) void fold_w_kernel(const float* __restrict__ W2,
                                                     const float* __restrict__ Wc,
                                                     const float* __restrict__ b2,
                                                     const float* __restrict__ bc,
                                                     float* __restrict__ W2c,
                                                     float* __restrict__ bc2) {
    int gid = blockIdx.x * 256 + threadIdx.x;  // 0..2047
    int r = gid >> 4, c = gid & 15;
    float acc = 0.f;
#pragma unroll 8
    for (int k = 0; k < 128; k++) acc += W2[r * 128 + k] * Wc[k * 16 + c];
    W2c[r * 16 + c] = acc;
    if (gid < 16) {
        float a = bc[gid];
        for (int k = 0; k < 128; k++) a += b2[k] * Wc[k * 16 + gid];
        bc2[gid] = a;
    }
}

// ---------------- GEMM 50000x128 @ 128x128, BK=32 tiling ----------------
// Block: 256 threads, 64 rows x 128 cols. Thread tile: 4 rows x 8 cols.
// LDS: sX 64x33 (8.4 KB) + sW 32x128 (16 KB) = 24.5 KB -> ~6 blocks/CU.
__global__ __launch_bounds__(256) void gemm128_kernel(const float* __restrict__ X,
                                                      const float* __restrict__ W,
                                                      float* __restrict__ Y, int M) {
    __shared__ float sX[64 * 33];
    __shared__ float sW[32 * 128];
    int tid = threadIdx.x;
    int r0 = blockIdx.x * 64;
    int colg = tid & 15, rowt = tid >> 4;

    float acc[4][8];
#pragma unroll
    for (int i = 0; i < 4; i++)
#pragma unroll
        for (int j = 0; j < 8; j++) acc[i][j] = 0.f;

    const float4* X4 = (const float4*)X;
    const float4* W4 = (const float4*)W;
    float4* sW4 = (float4*)sW;

#pragma unroll
    for (int kt = 0; kt < 4; kt++) {
        // stage X tile: 64 rows x 32 k = 512 float4
#pragma unroll
        for (int i = 0; i < 2; i++) {
            int idx = tid + i * 256;
            int row = idx >> 3, k4 = idx & 7;
            float4 v = make_float4(0.f, 0.f, 0.f, 0.f);
            if (r0 + row < M) v = X4[(size_t)(r0 + row) * 32 + kt * 8 + k4];
            float* p = &sX[row * 33 + k4 * 4];
            p[0] = v.x; p[1] = v.y; p[2] = v.z; p[3] = v.w;
        }
        // stage W tile: 32 k x 128 c = 1024 float4
#pragma unroll
        for (int i = 0; i < 4; i++) {
            int idx = tid + i * 256;
            int kk = idx >> 5, c4 = idx & 31;
            sW4[kk * 32 + c4] = W4[(size_t)(kt * 32 + kk) * 32 + c4];
        }
        __syncthreads();

#pragma unroll 8
        for (int k = 0; k < 32; k++) {
            float4 w0 = sW4[k * 32 + colg * 2];
            float4 w1 = sW4[k * 32 + colg * 2 + 1];
            float xs[4];
#pragma unroll
            for (int i = 0; i < 4; i++) xs[i] = sX[(rowt * 4 + i) * 33 + k];
#pragma unroll
            for (int i = 0; i < 4; i++) {
                acc[i][0] += xs[i] * w0.x; acc[i][1] += xs[i] * w0.y;
                acc[i][2] += xs[i] * w0.z; acc[i][3] += xs[i] * w0.w;
                acc[i][4] += xs[i] * w1.x; acc[i][5] += xs[i] * w1.y;
                acc[i][6] += xs[i] * w1.z; acc[i][7] += xs[i] * w1.w;
            }
        }
        __syncthreads();
    }

    int c = colg * 8;
#pragma unroll
    for (int i = 0; i < 4; i++) {
        int row = r0 + rowt * 4 + i;
        if (row < M) {
            float4* Yp = (float4*)(Y + (size_t)row * 128 + c);
            Yp[0] = make_float4(acc[i][0], acc[i][1], acc[i][2], acc[i][3]);
            Yp[1] = make_float4(acc[i][4], acc[i][5], acc[i][6], acc[i][7]);
        }
    }
}

// ---------------- Layer-1 aggregation (wave/node, 128-wide) + bias + BN + ReLU ----------------
__global__ __launch_bounds__(256) void aggregate_kernel(const float* __restrict__ H,
                                                        const int* __restrict__ csr_src,
                                                        const int* __restrict__ offs,
                                                        const float* __restrict__ dinv,
                                                        const float* __restrict__ bias,
                                                        const float* __restrict__ bn_mean,
                                                        const float* __restrict__ bn_var,
                                                        const float* __restrict__ bn_gamma,
                                                        const float* __restrict__ bn_beta,
                                                        float* __restrict__ Y) {
    int wv = threadIdx.x >> 6, lane = threadIdx.x & 63;
    int node = blockIdx.x * 4 + wv;            // 12500*4 == 50000
    int beg = offs[node], end = offs[node + 1];
    float di = dinv[node];

    float2 hv = ((const float2*)(H + (size_t)node * FDIM))[lane];
    float2 acc;
    acc.x = hv.x * di * di;                    // self loop: norm = dinv^2
    acc.y = hv.y * di * di;

    int e = beg;
    for (; e + 3 < end; e += 4) {
        int s0 = csr_src[e], s1 = csr_src[e + 1], s2 = csr_src[e + 2], s3 = csr_src[e + 3];
        float w0 = dinv[s0] * di, w1 = dinv[s1] * di, w2 = dinv[s2] * di, w3 = dinv[s3] * di;
        float2 v0 = ((const float2*)(H + (size_t)s0 * FDIM))[lane];
        float2 v1 = ((const float2*)(H + (size_t)s1 * FDIM))[lane];
        float2 v2 = ((const float2*)(H + (size_t)s2 * FDIM))[lane];
        float2 v3 = ((const float2*)(H + (size_t)s3 * FDIM))[lane];
        acc.x += v0.x * w0 + v1.x * w1 + v2.x * w2 + v3.x * w3;
        acc.y += v0.y * w0 + v1.y * w1 + v2.y * w2 + v3.y * w3;
    }
    for (; e < end; e++) {
        int s0 = csr_src[e];
        float w0 = dinv[s0] * di;
        float2 v0 = ((const float2*)(H + (size_t)s0 * FDIM))[lane];
        acc.x += v0.x * w0;
        acc.y += v0.y * w0;
    }

    int c0 = lane * 2, c1 = c0 + 1;
    acc.x += bias[c0];
    acc.y += bias[c1];
    float sc0 = bn_gamma[c0] * rsqrtf(bn_var[c0] + BN_EPS);
    float sc1 = bn_gamma[c1] * rsqrtf(bn_var[c1] + BN_EPS);
    acc.x = fmaxf((acc.x - bn_mean[c0]) * sc0 + bn_beta[c0], 0.f);
    acc.y = fmaxf((acc.y - bn_mean[c1]) * sc1 + bn_beta[c1], 0.f);
    ((float2*)(Y + (size_t)node * FDIM))[lane] = acc;
}

// ---------------- Z = x2 @ W2c  (50000x128 @ 128x16) ----------------
__global__ __launch_bounds__(256) void gemmZ_kernel(const float* __restrict__ X,
                                                    const float* __restrict__ W,
                                                    float* __restrict__ Z, int M) {
    __shared__ float sX[16 * 132];
    __shared__ float sW[128 * 16];
    int tid = threadIdx.x;

    const float4* W4 = (const float4*)W;
    float4* sW4 = (float4*)sW;
    sW4[tid] = W4[tid];
    sW4[tid + 256] = W4[tid + 256];

    int r0 = blockIdx.x * 16;
    const float4* X4 = (const float4*)X;
#pragma unroll
    for (int i = 0; i < 2; i++) {
        int fi = tid + i * 256;
        int row = fi >> 5, c4 = fi & 31;
        float4 v = make_float4(0.f, 0.f, 0.f, 0.f);
        if (r0 + row < M) v = X4[(size_t)(r0 + row) * 32 + c4];
        float* p = &sX[row * 132 + c4 * 4];
        p[0] = v.x; p[1] = v.y; p[2] = v.z; p[3] = v.w;
    }
    __syncthreads();

    int c = tid & 15, rl = tid >> 4;
    int row = r0 + rl;
    float acc = 0.f;
#pragma unroll 8
    for (int k = 0; k < 128; k++) acc += sX[rl * 132 + k] * sW[k * 16 + c];
    if (row < M) Z[(size_t)row * NCLS + c] = acc;
}

// ---------------- Layer-2 aggregation (16-wide) + bc2 -> out ----------------
__global__ __launch_bounds__(256) void agg2_kernel(const float* __restrict__ Z,
                                                   const int* __restrict__ csr_src,
                                                   const int* __restrict__ offs,
                                                   const float* __restrict__ dinv,
                                                   const float* __restrict__ bc2,
                                                   float* __restrict__ out) {
    int grp = threadIdx.x >> 4, c = threadIdx.x & 15;
    int node = blockIdx.x * 16 + grp;          // 3125*16 == 50000
    int beg = offs[node], end = offs[node + 1];
    float di = dinv[node];

    float acc = Z[(size_t)node * NCLS + c] * di * di;
    int e = beg;
    for (; e + 1 < end; e += 2) {
        int s0 = csr_src[e], s1 = csr_src[e + 1];
        float w0 = dinv[s0] * di, w1 = dinv[s1] * di;
        acc += Z[(size_t)s0 * NCLS + c] * w0 + Z[(size_t)s1 * NCLS + c] * w1;
    }
    if (e < end) {
        int s0 = csr_src[e];
        acc += Z[(size_t)s0 * NCLS + c] * (dinv[s0] * di);
    }
    out[(size_t)node * NCLS + c] = acc + bc2[c];
}

// ---------------- Launch ----------------
extern "C" void kernel_launch(void* const* d_in, const int* in_sizes, int n_in,
                              void* d_out, int out_size, void* d_ws, size_t ws_size,
                              hipStream_t stream) {
    const float* seq   = (const float*)d_in[0];
    const int*   eidx  = (const int*)d_in[1];
    const float* W1    = (const float*)d_in[2];
    const float* b1    = (const float*)d_in[3];
    const float* gamma = (const float*)d_in[4];
    const float* beta  = (const float*)d_in[5];
    const float* rmean = (const float*)d_in[6];
    const float* rvar  = (const float*)d_in[7];
    const float* W2    = (const float*)d_in[8];
    const float* b2    = (const float*)d_in[9];
    const float* Wc    = (const float*)d_in[10];
    const float* bc    = (const float*)d_in[11];
    float* out = (float*)d_out;

    const int* src = eidx;            // edge_index[0]
    const int* dst = eidx + N_EDGES;  // edge_index[1]

    char* ws = (char*)d_ws;
    size_t off = 0;
    auto alloc = [&](size_t bytes) -> void* {
        void* p = ws + off;
        off = (off + bytes + 255) & ~(size_t)255;
        return p;
    };
    int*   deg      = (int*)alloc(N_NODES * 4);
    int*   cursor   = (int*)alloc(N_NODES * 4);
    int*   offs     = (int*)alloc((N_NODES + 1) * 4);
    int*   partials = (int*)alloc(256 * 4);
    float* dinv     = (float*)alloc(N_NODES * 4);
    int*   csr_src  = (int*)alloc(N_EDGES * 4);
    float* W2c      = (float*)alloc(FDIM * NCLS * 4);
    float* bc2      = (float*)alloc(NCLS * 4);
    float* bufA     = (float*)alloc((size_t)N_NODES * FDIM * 4);
    float* bufB     = (float*)alloc((size_t)N_NODES * FDIM * 4);
    float* Zbuf     = (float*)alloc((size_t)N_NODES * NCLS * 4);

    const int NB_N = (N_NODES + 255) / 256;   // 196
    const int NB_E = (N_EDGES + 255) / 256;   // 2500

    zero_kernel<<<NB_N, 256, 0, stream>>>(deg, cursor);
    count_deg_kernel<<<NB_E, 256, 0, stream>>>(dst, deg);
    scan_block_kernel<<<NB_N, 256, 0, stream>>>(deg, offs, partials, dinv);
    scan_partials_kernel<<<1, 256, 0, stream>>>(partials, offs, NB_N);
    scan_add_kernel<<<NB_N, 256, 0, stream>>>(offs, partials);
    fill_csr_kernel<<<NB_E, 256, 0, stream>>>(src, dst, offs, cursor, csr_src);
    fold_w_kernel<<<8, 256, 0, stream>>>(W2, Wc, b2, bc, W2c, bc2);

    // layer 1: h = seq @ W1 ; agg + b1 + BN + ReLU
    gemm128_kernel<<<(N_NODES + 63) / 64, 256, 0, stream>>>(seq, W1, bufA, N_NODES);
    aggregate_kernel<<<N_NODES / 4, 256, 0, stream>>>(bufA, csr_src, offs, dinv,
                                                      b1, rmean, rvar, gamma, beta, bufB);
    // layer 2 folded with classifier: Z = x2 @ (W2@Wc); out = A·Z + bc2
    gemmZ_kernel<<<(N_NODES + 15) / 16, 256, 0, stream>>>(bufB, W2c, Zbuf, N_NODES);
    agg2_kernel<<<(N_NODES + 15) / 16, 256, 0, stream>>>(Zbuf, csr_src, offs, dinv, bc2, out);
}

// Round 3
// 260.303 us; speedup vs baseline: 1.5080x; 1.0807x over previous
//
#include <hip/hip_runtime.h>
#include <math.h>

#define N_NODES 50000
#define N_EDGES 640000
#define FDIM 128
#define NCLS 16
#define BN_EPS 1e-5f

// ---- bf16 pack/unpack (RNE) ----
__device__ __forceinline__ unsigned pack_bf16x2(float lo, float hi) {
    unsigned ul = __float_as_uint(lo);
    unsigned uh = __float_as_uint(hi);
    ul += 0x7fff + ((ul >> 16) & 1);
    uh += 0x7fff + ((uh >> 16) & 1);
    return (ul >> 16) | (uh & 0xffff0000u);
}
__device__ __forceinline__ float bf_lo(unsigned u) { return __uint_as_float(u << 16); }
__device__ __forceinline__ float bf_hi(unsigned u) { return __uint_as_float(u & 0xffff0000u); }

// ---------------- CSR build ----------------

__global__ __launch_bounds__(256) void count_deg_kernel(const int* __restrict__ dst, int* __restrict__ deg) {
    int gid = blockIdx.x * 256 + threadIdx.x;
    if (gid < N_EDGES) atomicAdd(&deg[dst[gid]], 1);
}

// block-local exclusive scan of deg (writes offs for gid<=N), block totals -> partials, dinv
__global__ __launch_bounds__(256) void scan_block_kernel(const int* __restrict__ deg,
                                                         int* __restrict__ offs,
                                                         int* __restrict__ partials,
                                                         float* __restrict__ dinv) {
    __shared__ int s[256];
    int tid = threadIdx.x;
    int gid = blockIdx.x * 256 + tid;
    int v = (gid < N_NODES) ? deg[gid] : 0;
    if (gid < N_NODES) dinv[gid] = rsqrtf((float)(v + 1));  // +1 self loop
    s[tid] = v;
    __syncthreads();
    for (int off = 1; off < 256; off <<= 1) {
        int t = (tid >= off) ? s[tid - off] : 0;
        __syncthreads();
        s[tid] += t;
        __syncthreads();
    }
    if (gid <= N_NODES) offs[gid] = s[tid] - v;   // block-local exclusive
    if (tid == 255) partials[blockIdx.x] = s[255];
}

// exclusive scan of 196 block totals, in place
__global__ __launch_bounds__(256) void scan_partials_kernel(int* __restrict__ partials, int nb) {
    __shared__ int s[256];
    int tid = threadIdx.x;
    int v = (tid < nb) ? partials[tid] : 0;
    s[tid] = v;
    __syncthreads();
    for (int off = 1; off < 256; off <<= 1) {
        int t = (tid >= off) ? s[tid - off] : 0;
        __syncthreads();
        s[tid] += t;
        __syncthreads();
    }
    if (tid < nb) partials[tid] = s[tid] - v;
}

__global__ __launch_bounds__(256) void fill_csr_kernel(const int* __restrict__ src,
                                                       const int* __restrict__ dst,
                                                       const int* __restrict__ offs,
                                                       const int* __restrict__ part,
                                                       const float* __restrict__ dinv,
                                                       int* __restrict__ cursor,
                                                       int* __restrict__ csr_src,
                                                       float* __restrict__ csr_w) {
    int gid = blockIdx.x * 256 + threadIdx.x;
    if (gid < N_EDGES) {
        int d = dst[gid];
        int s = src[gid];
        int pos = offs[d] + part[d >> 8] + atomicAdd(&cursor[d], 1);
        csr_src[pos] = s;
        csr_w[pos] = dinv[s];
    }
}

// ---------------- fold: W2c = W2@Wc, bc2 = b2@Wc + bc, BN affine per lane ----------------
__global__ __launch_bounds__(256) void fold_w_kernel(const float* __restrict__ W2,
                                                     const float* __restrict__ Wc,
                                                     const float* __restrict__ b1,
                                                     const float* __restrict__ b2,
                                                     const float* __restrict__ bc,
                                                     const float* __restrict__ gamma,
                                                     const float* __restrict__ beta,
                                                     const float* __restrict__ rmean,
                                                     const float* __restrict__ rvar,
                                                     float* __restrict__ W2c,
                                                     float* __restrict__ bc2,
                                                     float4* __restrict__ fusedq) {
    int gid = blockIdx.x * 256 + threadIdx.x;  // 0..2047
    int r = gid >> 4, c = gid & 15;
    float acc = 0.f;
#pragma unroll 8
    for (int k = 0; k < 128; k++) acc += W2[r * 128 + k] * Wc[k * 16 + c];
    W2c[gid] = acc;
    if (blockIdx.x == 0) {
        int tid = threadIdx.x;
        if (tid < 16) {
            float a = bc[tid];
            for (int k = 0; k < 128; k++) a += b2[k] * Wc[k * 16 + tid];
            bc2[tid] = a;
        }
        if (tid < 64) {
            int c0 = tid * 2, c1 = c0 + 1;
            float sc0 = gamma[c0] * rsqrtf(rvar[c0] + BN_EPS);
            float sc1 = gamma[c1] * rsqrtf(rvar[c1] + BN_EPS);
            float sh0 = (b1[c0] - rmean[c0]) * sc0 + beta[c0];
            float sh1 = (b1[c1] - rmean[c1]) * sc1 + beta[c1];
            fusedq[tid] = make_float4(sc0, sh0, sc1, sh1);
        }
    }
}

// ---------------- GEMM 50000x128 @ 128x128 -> bf16 out ----------------
// Block: 256 threads, 64 rows x 128 cols. Thread tile: 4 rows x 8 cols. BK=32.
__global__ __launch_bounds__(256) void gemm128_kernel(const float* __restrict__ X,
                                                      const float* __restrict__ W,
                                                      unsigned* __restrict__ Yb, int M) {
    __shared__ float sX[64 * 33];
    __shared__ float sW[32 * 128];
    int tid = threadIdx.x;
    int r0 = blockIdx.x * 64;
    int colg = tid & 15, rowt = tid >> 4;

    float acc[4][8];
#pragma unroll
    for (int i = 0; i < 4; i++)
#pragma unroll
        for (int j = 0; j < 8; j++) acc[i][j] = 0.f;

    const float4* X4 = (const float4*)X;
    const float4* W4 = (const float4*)W;
    float4* sW4 = (float4*)sW;

#pragma unroll
    for (int kt = 0; kt < 4; kt++) {
#pragma unroll
        for (int i = 0; i < 2; i++) {
            int idx = tid + i * 256;
            int row = idx >> 3, k4 = idx & 7;
            float4 v = make_float4(0.f, 0.f, 0.f, 0.f);
            if (r0 + row < M) v = X4[(size_t)(r0 + row) * 32 + kt * 8 + k4];
            float* p = &sX[row * 33 + k4 * 4];
            p[0] = v.x; p[1] = v.y; p[2] = v.z; p[3] = v.w;
        }
#pragma unroll
        for (int i = 0; i < 4; i++) {
            int idx = tid + i * 256;
            int kk = idx >> 5, c4 = idx & 31;
            sW4[kk * 32 + c4] = W4[(size_t)(kt * 32 + kk) * 32 + c4];
        }
        __syncthreads();

#pragma unroll 8
        for (int k = 0; k < 32; k++) {
            float4 w0 = sW4[k * 32 + colg * 2];
            float4 w1 = sW4[k * 32 + colg * 2 + 1];
            float xs[4];
#pragma unroll
            for (int i = 0; i < 4; i++) xs[i] = sX[(rowt * 4 + i) * 33 + k];
#pragma unroll
            for (int i = 0; i < 4; i++) {
                acc[i][0] += xs[i] * w0.x; acc[i][1] += xs[i] * w0.y;
                acc[i][2] += xs[i] * w0.z; acc[i][3] += xs[i] * w0.w;
                acc[i][4] += xs[i] * w1.x; acc[i][5] += xs[i] * w1.y;
                acc[i][6] += xs[i] * w1.z; acc[i][7] += xs[i] * w1.w;
            }
        }
        __syncthreads();
    }

#pragma unroll
    for (int i = 0; i < 4; i++) {
        int row = r0 + rowt * 4 + i;
        if (row < M) {
            uint4 pv;
            pv.x = pack_bf16x2(acc[i][0], acc[i][1]);
            pv.y = pack_bf16x2(acc[i][2], acc[i][3]);
            pv.z = pack_bf16x2(acc[i][4], acc[i][5]);
            pv.w = pack_bf16x2(acc[i][6], acc[i][7]);
            *((uint4*)(Yb + (size_t)row * 64 + colg * 4)) = pv;
        }
    }
}

// ---------------- Layer-1 agg (bf16 gather) + BN + ReLU + @W2c -> Z ----------------
__global__ __launch_bounds__(256) void agg1_kernel(const unsigned* __restrict__ Hb,
                                                   const int* __restrict__ csr_src,
                                                   const float* __restrict__ csr_w,
                                                   const int* __restrict__ offs,
                                                   const int* __restrict__ part,
                                                   const float* __restrict__ dinv,
                                                   const float4* __restrict__ fusedq,
                                                   const float* __restrict__ W2c,
                                                   float* __restrict__ Z) {
    __shared__ float sH[4][128];
    int w = threadIdx.x >> 6, l = threadIdx.x & 63;
    int node = blockIdx.x * 4 + w;             // 12500*4 == 50000
    int beg = offs[node] + part[node >> 8];
    int end = offs[node + 1] + part[(node + 1) >> 8];
    float di = dinv[node];

    // preload W2c slice: lane (c = l&15, q = l>>4) owns k = q*32 .. q*32+31 of column c
    int c = l & 15, q = l >> 4;
    float wreg[32];
#pragma unroll
    for (int i = 0; i < 32; i++) wreg[i] = W2c[(q * 32 + i) * 16 + c];

    unsigned hv = Hb[(size_t)node * 64 + l];
    float n2 = di * di;
    float acc0 = bf_lo(hv) * n2, acc1 = bf_hi(hv) * n2;

    int e = beg;
    for (; e + 3 < end; e += 4) {
        int s0 = csr_src[e], s1 = csr_src[e + 1], s2 = csr_src[e + 2], s3 = csr_src[e + 3];
        float w0 = csr_w[e] * di, w1 = csr_w[e + 1] * di;
        float w2 = csr_w[e + 2] * di, w3 = csr_w[e + 3] * di;
        unsigned u0 = Hb[(size_t)s0 * 64 + l];
        unsigned u1 = Hb[(size_t)s1 * 64 + l];
        unsigned u2 = Hb[(size_t)s2 * 64 + l];
        unsigned u3 = Hb[(size_t)s3 * 64 + l];
        acc0 += bf_lo(u0) * w0 + bf_lo(u1) * w1 + bf_lo(u2) * w2 + bf_lo(u3) * w3;
        acc1 += bf_hi(u0) * w0 + bf_hi(u1) * w1 + bf_hi(u2) * w2 + bf_hi(u3) * w3;
    }
    for (; e < end; e++) {
        int s0 = csr_src[e];
        float w0 = csr_w[e] * di;
        unsigned u0 = Hb[(size_t)s0 * 64 + l];
        acc0 += bf_lo(u0) * w0;
        acc1 += bf_hi(u0) * w0;
    }

    float4 qv = fusedq[l];
    float a0 = fmaxf(acc0 * qv.x + qv.y, 0.f);
    float a1 = fmaxf(acc1 * qv.z + qv.w, 0.f);

    // in-wave transpose through LDS (no barrier needed: wave-private region)
    ((float2*)sH[w])[l] = make_float2(a0, a1);
    float z = 0.f;
    const float4* row4 = (const float4*)&sH[w][q * 32];
#pragma unroll
    for (int i = 0; i < 8; i++) {
        float4 v = row4[i];
        z += v.x * wreg[i * 4] + v.y * wreg[i * 4 + 1] + v.z * wreg[i * 4 + 2] + v.w * wreg[i * 4 + 3];
    }
    z += __shfl_xor(z, 16);
    z += __shfl_xor(z, 32);
    if (l < 16) Z[(size_t)node * NCLS + l] = z;
}

// ---------------- Layer-2 agg (16-wide on Z) + bc2 -> out ----------------
__global__ __launch_bounds__(256) void agg2_kernel(const float* __restrict__ Z,
                                                   const int* __restrict__ csr_src,
                                                   const float* __restrict__ csr_w,
                                                   const int* __restrict__ offs,
                                                   const int* __restrict__ part,
                                                   const float* __restrict__ dinv,
                                                   const float* __restrict__ bc2,
                                                   float* __restrict__ out) {
    int grp = threadIdx.x >> 4, c = threadIdx.x & 15;
    int node = blockIdx.x * 16 + grp;          // 3125*16 == 50000
    int beg = offs[node] + part[node >> 8];
    int end = offs[node + 1] + part[(node + 1) >> 8];
    float di = dinv[node];

    float acc = Z[(size_t)node * NCLS + c] * di * di;
    int e = beg;
    for (; e + 3 < end; e += 4) {
        int s0 = csr_src[e], s1 = csr_src[e + 1], s2 = csr_src[e + 2], s3 = csr_src[e + 3];
        float w0 = csr_w[e] * di, w1 = csr_w[e + 1] * di;
        float w2 = csr_w[e + 2] * di, w3 = csr_w[e + 3] * di;
        acc += Z[(size_t)s0 * NCLS + c] * w0 + Z[(size_t)s1 * NCLS + c] * w1
             + Z[(size_t)s2 * NCLS + c] * w2 + Z[(size_t)s3 * NCLS + c] * w3;
    }
    for (; e < end; e++) {
        acc += Z[(size_t)csr_src[e] * NCLS + c] * (csr_w[e] * di);
    }
    out[(size_t)node * NCLS + c] = acc + bc2[c];
}

// ---------------- Launch ----------------
extern "C" void kernel_launch(void* const* d_in, const int* in_sizes, int n_in,
                              void* d_out, int out_size, void* d_ws, size_t ws_size,
                              hipStream_t stream) {
    const float* seq   = (const float*)d_in[0];
    const int*   eidx  = (const int*)d_in[1];
    const float* W1    = (const float*)d_in[2];
    const float* b1    = (const float*)d_in[3];
    const float* gamma = (const float*)d_in[4];
    const float* beta  = (const float*)d_in[5];
    const float* rmean = (const float*)d_in[6];
    const float* rvar  = (const float*)d_in[7];
    const float* W2    = (const float*)d_in[8];
    const float* b2    = (const float*)d_in[9];
    const float* Wc    = (const float*)d_in[10];
    const float* bc    = (const float*)d_in[11];
    float* out = (float*)d_out;

    const int* src = eidx;            // edge_index[0]
    const int* dst = eidx + N_EDGES;  // edge_index[1]

    char* ws = (char*)d_ws;
    size_t off = 0;
    auto alloc = [&](size_t bytes) -> void* {
        void* p = ws + off;
        off = (off + bytes + 255) & ~(size_t)255;
        return p;
    };
    int*    degcur   = (int*)alloc((size_t)2 * N_NODES * 4);  // deg | cursor (one memset)
    int*    deg      = degcur;
    int*    cursor   = degcur + N_NODES;
    int*    offs     = (int*)alloc((N_NODES + 1) * 4);
    int*    partials = (int*)alloc(256 * 4);
    float*  dinv     = (float*)alloc(N_NODES * 4);
    int*    csr_src  = (int*)alloc((size_t)N_EDGES * 4);
    float*  csr_w    = (float*)alloc((size_t)N_EDGES * 4);
    float*  W2c      = (float*)alloc(FDIM * NCLS * 4);
    float*  bc2      = (float*)alloc(NCLS * 4);
    float4* fusedq   = (float4*)alloc(64 * 16);
    unsigned* bufA   = (unsigned*)alloc((size_t)N_NODES * (FDIM / 2) * 4);  // bf16 packed
    float*  Zbuf     = (float*)alloc((size_t)N_NODES * NCLS * 4);

    const int NB_N = (N_NODES + 255) / 256;   // 196
    const int NB_E = (N_EDGES + 255) / 256;   // 2500

    hipMemsetAsync(degcur, 0, (size_t)2 * N_NODES * 4, stream);
    count_deg_kernel<<<NB_E, 256, 0, stream>>>(dst, deg);
    scan_block_kernel<<<NB_N, 256, 0, stream>>>(deg, offs, partials, dinv);
    scan_partials_kernel<<<1, 256, 0, stream>>>(partials, NB_N);
    fill_csr_kernel<<<NB_E, 256, 0, stream>>>(src, dst, offs, partials, dinv,
                                              cursor, csr_src, csr_w);
    fold_w_kernel<<<8, 256, 0, stream>>>(W2, Wc, b1, b2, bc, gamma, beta, rmean, rvar,
                                         W2c, bc2, fusedq);

    gemm128_kernel<<<(N_NODES + 63) / 64, 256, 0, stream>>>(seq, W1, bufA, N_NODES);
    agg1_kernel<<<N_NODES / 4, 256, 0, stream>>>(bufA, csr_src, csr_w, offs, partials,
                                                 dinv, fusedq, W2c, Zbuf);
    agg2_kernel<<<N_NODES / 16, 256, 0, stream>>>(Zbuf, csr_src, csr_w, offs, partials,
                                                  dinv, bc2, out);
}